// Round 4
// baseline (228.068 us; speedup 1.0000x reference)
//
#include <hip/hip_runtime.h>
#include <hip/hip_bf16.h>
#include <math.h>

#define BATCH 32
#define NTOK 577
#define NPATCH 576
#define CDIM 768
#define HEADS 12
#define DHEAD 64
#define W3 2304
#define FT 404

// ---- workspace layout (float offsets) ----
#define WS_WTIL  24576      // 32*12*768         -> 319488
#define WS_DBIAS 319488     // 32*12             -> 319872
#define WS_DOTS  319872     // 32*12*577         -> 541440
#define WS_IND   541440     // 32*404 (as int)   -> 554368

// ---- output layout (FLOAT32 element offsets; d_out is float*) ----
#define O_X      0ULL           // 32*577*768 = 14180352
#define O_INDEX  14180352ULL    // 32*404*768 = 9928704 -> 24109056
#define O_IND    24109056ULL    // 32*404     = 12928   -> 24121984
#define O_CA     24121984ULL    // 32*576     = 18432   -> 24140416
#define O_FT     24140416ULL

// K_fold: per (b,h): q[d] = x[b,0,:]·W_qkv[:, h*64+d] + b_qkv[h*64+d]
//         wtil[b,h,c] = sum_d q[d] * W_qkv[c, 768 + h*64 + d]
//         dbias[b,h]  = sum_d q[d] * b_qkv[768 + h*64 + d]
__global__ __launch_bounds__(256) void k_fold(const float* __restrict__ x,
                                              const float* __restrict__ W,
                                              const float* __restrict__ bias,
                                              float* __restrict__ wtil,
                                              float* __restrict__ dbias) {
    __shared__ float x0s[CDIM];   // CLS token, 3 KB
    __shared__ float red[256];
    __shared__ float qs[DHEAD];
    const int b = blockIdx.x, h = blockIdx.y, tid = threadIdx.x;
    for (int i = tid; i < CDIM; i += 256) x0s[i] = x[(size_t)b * NTOK * CDIM + i];
    __syncthreads();
    // q-part: thread (seg,d) sums c in [seg*192,(seg+1)*192) of x0[c]*W[c, h*64+d]
    {
        const int d = tid & 63, seg = tid >> 6;
        const float* Wq = W + (size_t)(h * DHEAD + d);
        float acc = 0.f;
        const int c0 = seg * 192;
        #pragma unroll 8
        for (int c = c0; c < c0 + 192; c++)
            acc += x0s[c] * Wq[(size_t)c * W3];
        red[tid] = acc;
    }
    __syncthreads();
    if (tid < DHEAD) {
        float q = red[tid] + red[tid + 64] + red[tid + 128] + red[tid + 192]
                + bias[h * DHEAD + tid];
        qs[tid] = q;
        float t = q * bias[CDIM + h * DHEAD + tid];
        #pragma unroll
        for (int off = 32; off; off >>= 1) t += __shfl_down(t, off);
        if (tid == 0) dbias[b * HEADS + h] = t;
    }
    __syncthreads();
    for (int c = tid; c < CDIM; c += 256) {
        const float* wr = W + (size_t)c * W3 + CDIM + h * DHEAD;
        float acc = 0.f;
        #pragma unroll
        for (int d = 0; d < DHEAD; d += 4) {
            float4 a = *reinterpret_cast<const float4*>(wr + d);
            acc += a.x * qs[d] + a.y * qs[d + 1] + a.z * qs[d + 2] + a.w * qs[d + 3];
        }
        wtil[((size_t)b * HEADS + h) * CDIM + c] = acc;
    }
}

// K_dots: dots[b,h,j] = 0.125*(x[b,j,:]·wtil[b,h,:] + dbias[b,h]); fused x->out0 copy
__global__ __launch_bounds__(256) void k_dots(const float* __restrict__ x,
                                              const float* __restrict__ wtil,
                                              const float* __restrict__ dbias,
                                              float* __restrict__ dots,
                                              float* __restrict__ out0) {
    __shared__ float wt[HEADS * CDIM];   // 36 KB
    __shared__ float db[HEADS];
    const int b = blockIdx.x, tid = threadIdx.x;
    for (int i = tid; i < HEADS * CDIM; i += 256) wt[i] = wtil[(size_t)b * HEADS * CDIM + i];
    if (tid < HEADS) db[tid] = dbias[b * HEADS + tid];
    __syncthreads();
    const int wave = tid >> 6, lane = tid & 63;
    for (int it = 0; it < 8; it++) {
        const int j = blockIdx.y * 32 + it * 4 + wave;
        if (j >= NTOK) break;
        const float4* xp = reinterpret_cast<const float4*>(x + ((size_t)b * NTOK + j) * CDIM);
        float4* op = reinterpret_cast<float4*>(out0 + ((size_t)b * NTOK + j) * CDIM);
        float acc[HEADS];
        #pragma unroll
        for (int h = 0; h < HEADS; h++) acc[h] = 0.f;
        #pragma unroll
        for (int i = 0; i < 3; i++) {
            float4 a = xp[i * 64 + lane];
            op[i * 64 + lane] = a;
            const int cbase = i * 256 + lane * 4;
            #pragma unroll
            for (int h = 0; h < HEADS; h++) {
                float4 w = *reinterpret_cast<const float4*>(&wt[h * CDIM + cbase]);
                acc[h] += a.x * w.x + a.y * w.y + a.z * w.z + a.w * w.w;
            }
        }
        #pragma unroll
        for (int off = 32; off; off >>= 1)
            #pragma unroll
            for (int h = 0; h < HEADS; h++) acc[h] += __shfl_xor(acc[h], off);
        if (lane == 0) {
            #pragma unroll
            for (int h = 0; h < HEADS; h++)
                dots[((size_t)b * HEADS + h) * NTOK + j] = 0.125f * (acc[h] + db[h]);
        }
    }
}

// K_catopk: per batch (768 thr = 12 waves): wave h does softmax stats for head h
// (shfl-only), then ca = mean_h softmax, rank-based top-404 (uint4 LDS reads),
// then shuffle-scan compaction (no serial LDS walks).
__global__ __launch_bounds__(768) void k_catopk(const float* __restrict__ dots,
                                                float* __restrict__ ca_out,
                                                float* __restrict__ ind_out,
                                                float* __restrict__ ft_out,
                                                int* __restrict__ ind_ws,
                                                int write_ft) {
    __shared__ float dl[HEADS * NTOK];   // 27.7 KB
    __shared__ float mh[HEADS], sh[HEADS];
    __shared__ unsigned int vals[NPATCH];
    __shared__ int wsum[12];
    const int b = blockIdx.x, tid = threadIdx.x;
    const int w = tid >> 6, lane = tid & 63;
    for (int i = tid; i < HEADS * NTOK; i += 768) dl[i] = dots[(size_t)b * HEADS * NTOK + i];
    __syncthreads();
    {
        // one wave per head: shfl-only max & sum
        const float* row = dl + w * NTOK;
        float m = -3.4e38f;
        for (int j = lane; j < NTOK; j += 64) m = fmaxf(m, row[j]);
        #pragma unroll
        for (int off = 32; off; off >>= 1) m = fmaxf(m, __shfl_xor(m, off));
        float s = 0.f;
        for (int j = lane; j < NTOK; j += 64) s += expf(row[j] - m);
        #pragma unroll
        for (int off = 32; off; off >>= 1) s += __shfl_xor(s, off);
        if (lane == 0) { mh[w] = m; sh[w] = s; }
    }
    __syncthreads();
    unsigned int myv = 0;
    if (tid < NPATCH) {
        float ca = 0.f;
        #pragma unroll
        for (int h = 0; h < HEADS; h++)
            ca += expf(dl[h * NTOK + 1 + tid] - mh[h]) / sh[h];
        ca *= (1.f / 12.f);
        ca_out[(size_t)b * NPATCH + tid] = ca;
        myv = __float_as_uint(ca);   // ca > 0 -> bit order == value order
        vals[tid] = myv;
    }
    __syncthreads();
    int f = 0;
    if (tid < NPATCH) {
        int rank = 0;
        const uint4* v4 = reinterpret_cast<const uint4*>(vals);
        #pragma unroll 4
        for (int jb = 0; jb < NPATCH / 4; jb++) {
            const uint4 v = v4[jb];
            const int j = jb * 4;
            rank += (v.x > myv) || (v.x == myv && (j + 0) < tid);
            rank += (v.y > myv) || (v.y == myv && (j + 1) < tid);
            rank += (v.z > myv) || (v.z == myv && (j + 2) < tid);
            rank += (v.w > myv) || (v.w == myv && (j + 3) < tid);
        }
        f = (rank < FT) ? 1 : 0;   // tie: lower index first (jax top_k)
    }
    // block-wide exclusive prefix sum of f: wave shfl-scan + wave-sum offsets
    int scan = f;
    #pragma unroll
    for (int off = 1; off < 64; off <<= 1) {
        const int n = __shfl_up(scan, off);
        if (lane >= off) scan += n;
    }
    if (lane == 63) wsum[w] = scan;
    __syncthreads();
    int woff = 0;
    for (int i = 0; i < w; i++) woff += wsum[i];
    if (f) {
        const int pos = woff + scan - 1;   // exclusive prefix (scan includes own f=1)
        ind_ws[b * FT + pos] = tid;
        ind_out[(size_t)b * FT + pos] = (float)tid;
    }
    if (b == 0 && tid == 0 && write_ft) ft_out[0] = (float)FT;
}

// K_bcast: index[b,t,c] = ind[b,t] broadcast over c, as f32
__global__ __launch_bounds__(256) void k_bcast(const int* __restrict__ ind,
                                               float* __restrict__ out1) {
    const unsigned int g = blockIdx.x * 256u + threadIdx.x;
    const unsigned int e = g * 4u;               // total = 9928704 = 9696*1024 exactly
    const unsigned int row = e / CDIM;           // b*FT + t
    const float v = (float)ind[row];
    float4 o; o.x = v; o.y = v; o.z = v; o.w = v;
    *reinterpret_cast<float4*>(out1 + e) = o;
}

extern "C" void kernel_launch(void* const* d_in, const int* in_sizes, int n_in,
                              void* d_out, int out_size, void* d_ws, size_t ws_size,
                              hipStream_t stream) {
    const float* x  = (const float*)d_in[0];
    const float* W  = (const float*)d_in[2];   // W_qkv [768, 2304]
    const float* bq = (const float*)d_in[3];   // b_qkv [2304]
    float* ws = (float*)d_ws;
    float* out = (float*)d_out;

    k_fold<<<dim3(BATCH, HEADS), 256, 0, stream>>>(x, W, bq, ws + WS_WTIL, ws + WS_DBIAS);
    k_dots<<<dim3(BATCH, 19), 256, 0, stream>>>(x, ws + WS_WTIL, ws + WS_DBIAS, ws + WS_DOTS, out + O_X);
    const int write_ft = (out_size > (int)O_FT) ? 1 : 0;
    k_catopk<<<BATCH, 768, 0, stream>>>(ws + WS_DOTS, out + O_CA, out + O_IND, out + O_FT,
                                        (int*)(ws + WS_IND), write_ft);
    k_bcast<<<9696, 256, 0, stream>>>((const int*)(ws + WS_IND), out + O_INDEX);
}